// Round 5
// baseline (547665.674 us; speedup 1.0000x reference)
//
#include <hip/hip_runtime.h>
#include <math.h>

#define B_TOT 2048
#define T_LEN 1024
#define HID   512
#define CH    9
#define CONDK 272            // 128 + 128 + 16
#define K1X   (2*CH)         // x part of GRU1 K
#define G3    1536           // 3*HID
#define ROWS  4              // batch rows per workgroup
#define NWG   (B_TOT/ROWS)   // 512 = 2 WGs per CU
#define NTHR  512

// ws layout (floats), k-major separate-plane weight panels (R2 layout)
#define SZ_W1T  ((HID + K1X) * G3)   // 530*1536
#define SZ_W2T  ((2*HID) * G3)       // 1024*1536
#define SZ_WHT  (CONDK * HID)
#define OFF_W1T 0
#define OFF_W2T (OFF_W1T + SZ_W1T)
#define OFF_WHT (OFF_W2T + SZ_W2T)

__global__ void prep_kernel(const float* __restrict__ w_ih1, const float* __restrict__ w_hh1,
                            const float* __restrict__ w_ih2, const float* __restrict__ w_hh2,
                            const float* __restrict__ W_h, float* __restrict__ ws)
{
    int i = blockIdx.x * blockDim.x + threadIdx.x;
    const int total = SZ_W1T + SZ_W2T + SZ_WHT;
    if (i >= total) return;
    if (i < SZ_W1T) {
        int k = i / G3, g = i % G3;
        ws[OFF_W1T + i] = (k < HID) ? w_hh1[g*HID + k] : w_ih1[g*K1X + (k - HID)];
    } else if (i < SZ_W1T + SZ_W2T) {
        int j = i - SZ_W1T;
        int k = j / G3, g = j % G3;
        ws[OFF_W2T + j] = (k < HID) ? w_hh2[g*HID + k] : w_ih2[g*HID + (k - HID)];
    } else {
        int j = i - SZ_W1T - SZ_W2T;
        int k = j / HID, u = j % HID;
        ws[OFF_WHT + j] = W_h[u*CONDK + k];
    }
}

__device__ __forceinline__ float sigmf(float x) { return 1.0f / (1.0f + expf(-x)); }

__global__ __launch_bounds__(NTHR, 4)   // 4 waves/EU -> 2 WGs/CU, VGPR cap 128
void note_decoder_kernel(const float* __restrict__ z, const float* __restrict__ se,
                         const float* __restrict__ skel, const float* __restrict__ cond,
                         const float* __restrict__ rnd,
                         const float* __restrict__ b_h,
                         const float* __restrict__ b_ih1, const float* __restrict__ b_hh1,
                         const float* __restrict__ b_ih2, const float* __restrict__ b_hh2,
                         const float* __restrict__ W_out, const float* __restrict__ b_out,
                         const float* __restrict__ ws,
                         float* __restrict__ out)
{
    // k-major state: h[k][b]; one ds_read_b128 per k covers all 4 rows
    __shared__ float h1s[HID][ROWS];
    __shared__ float h2s[HID][ROWS];
    __shared__ float xf[2*CH][ROWS];      // x = [out(9) | skel(9)], k-major
    __shared__ float wouts[HID][CH];

    const float* __restrict__ W1t = ws + OFF_W1T;
    const float* __restrict__ W2t = ws + OFF_W2T;
    const float* __restrict__ Wht = ws + OFF_WHT;

    const int tid  = threadIdx.x;          // owns hidden unit `tid`
    const int row0 = blockIdx.x * ROWS;

    // stage W_out as [u][c]
    for (int i = tid; i < CH*HID; i += NTHR) {
        int c = i / HID, u = i % HID;
        wouts[u][c] = W_out[i];
    }
    // stage zc = [z | skel_encoded | cond] into h2s scratch, k-major
    for (int i = tid; i < ROWS*CONDK; i += NTHR) {
        int b = i / CONDK, k = i % CONDK;
        float v;
        if (k < 128)       v = z[(row0 + b)*128 + k];
        else if (k < 256)  v = se[(row0 + b)*128 + (k - 128)];
        else               v = cond[(row0 + b)*16 + (k - 256)];
        h2s[k][b] = v;
    }
    if (tid < ROWS*CH) xf[tid % CH][tid / CH] = 0.0f;   // out0 = 0 (xf[c][b])
    __syncthreads();

    // h1_0 = tanh(zc @ W_h^T + b_h)   (sequential k per (u,b): R2 order)
    {
        float acc[ROWS] = {0.f, 0.f, 0.f, 0.f};
        #pragma unroll 4
        for (int k = 0; k < CONDK; ++k) {
            float w = Wht[k*HID + tid];
            float4 a = *(const float4*)&h2s[k][0];
            acc[0] = fmaf(a.x, w, acc[0]);
            acc[1] = fmaf(a.y, w, acc[1]);
            acc[2] = fmaf(a.z, w, acc[2]);
            acc[3] = fmaf(a.w, w, acc[3]);
        }
        float bh = b_h[tid];
        __syncthreads();   // done reading zc scratch
        #pragma unroll
        for (int b = 0; b < ROWS; ++b) acc[b] = tanhf(acc[b] + bh);
        *(float4*)&h1s[tid][0] = make_float4(acc[0], acc[1], acc[2], acc[3]);
    }
    __syncthreads();

    // hoisted biases
    const float br1 = b_ih1[tid]         + b_hh1[tid];
    const float bz1 = b_ih1[HID + tid]   + b_hh1[HID + tid];
    const float bi1 = b_ih1[2*HID + tid];
    const float bn1 = b_hh1[2*HID + tid];
    const float br2 = b_ih2[tid]         + b_hh2[tid];
    const float bz2 = b_ih2[HID + tid]   + b_hh2[HID + tid];
    const float bi2 = b_ih2[2*HID + tid];
    const float bn2 = b_hh2[2*HID + tid];

    const int wv = tid >> 6, ln = tid & 63;

    for (int t = 0; t < T_LEN; ++t) {
        // stage skel half of x; feedback xf[0..8] from prev step
        if (tid < ROWS*CH) {
            int b = tid / CH, c = tid % CH;
            xf[CH + c][b] = skel[((size_t)(row0 + b)*T_LEN + t)*CH + c];
        }
        __syncthreads();                                   // A

        // ---- GRU1 ----
        float ar[ROWS], az[ROWS], ai[ROWS], ah[ROWS];
        #pragma unroll
        for (int b = 0; b < ROWS; ++b) { ar[b]=0.f; az[b]=0.f; ai[b]=0.f; ah[b]=0.f; }
        #pragma unroll 4
        for (int k = 0; k < HID; ++k) {                  // h-part -> r,z,hn
            const float* wr = W1t + (size_t)k*G3;
            float w_r = wr[tid], w_z = wr[HID + tid], w_n = wr[2*HID + tid];
            float4 a = *(const float4*)&h1s[k][0];
            ar[0]=fmaf(a.x,w_r,ar[0]); az[0]=fmaf(a.x,w_z,az[0]); ah[0]=fmaf(a.x,w_n,ah[0]);
            ar[1]=fmaf(a.y,w_r,ar[1]); az[1]=fmaf(a.y,w_z,az[1]); ah[1]=fmaf(a.y,w_n,ah[1]);
            ar[2]=fmaf(a.z,w_r,ar[2]); az[2]=fmaf(a.z,w_z,az[2]); ah[2]=fmaf(a.z,w_n,ah[2]);
            ar[3]=fmaf(a.w,w_r,ar[3]); az[3]=fmaf(a.w,w_z,az[3]); ah[3]=fmaf(a.w,w_n,ah[3]);
        }
        #pragma unroll
        for (int k = 0; k < K1X; ++k) {                  // x-part -> r,z,in
            const float* wr = W1t + (size_t)(HID + k)*G3;
            float w_r = wr[tid], w_z = wr[HID + tid], w_n = wr[2*HID + tid];
            float4 a = *(const float4*)&xf[k][0];
            ar[0]=fmaf(a.x,w_r,ar[0]); az[0]=fmaf(a.x,w_z,az[0]); ai[0]=fmaf(a.x,w_n,ai[0]);
            ar[1]=fmaf(a.y,w_r,ar[1]); az[1]=fmaf(a.y,w_z,az[1]); ai[1]=fmaf(a.y,w_n,ai[1]);
            ar[2]=fmaf(a.z,w_r,ar[2]); az[2]=fmaf(a.z,w_z,az[2]); ai[2]=fmaf(a.z,w_n,ai[2]);
            ar[3]=fmaf(a.w,w_r,ar[3]); az[3]=fmaf(a.w,w_z,az[3]); ai[3]=fmaf(a.w,w_n,ai[3]);
        }
        float4 p = *(const float4*)&h1s[tid][0];
        float h1old[ROWS] = {p.x, p.y, p.z, p.w};
        float h1n[ROWS];
        #pragma unroll
        for (int b = 0; b < ROWS; ++b) {
            float r  = sigmf(ar[b] + br1);
            float zg = sigmf(az[b] + bz1);
            float n  = tanhf(fmaf(r, ah[b] + bn1, ai[b] + bi1));
            h1n[b] = (1.0f - zg)*n + zg*h1old[b];
        }
        __syncthreads();                                   // B: h1 reads done
        *(float4*)&h1s[tid][0] = make_float4(h1n[0], h1n[1], h1n[2], h1n[3]);
        if (t == 0)                                        // hx[1] = hx[0] at i==0
            *(float4*)&h2s[tid][0] = make_float4(h1n[0], h1n[1], h1n[2], h1n[3]);
        __syncthreads();                                   // C

        // ---- GRU2: input = h1(new), hidden = h2 ----
        #pragma unroll
        for (int b = 0; b < ROWS; ++b) { ar[b]=0.f; az[b]=0.f; ai[b]=0.f; ah[b]=0.f; }
        #pragma unroll 4
        for (int k = 0; k < HID; ++k) {                  // h2-part -> r,z,hn
            const float* wr = W2t + (size_t)k*G3;
            float w_r = wr[tid], w_z = wr[HID + tid], w_n = wr[2*HID + tid];
            float4 a = *(const float4*)&h2s[k][0];
            ar[0]=fmaf(a.x,w_r,ar[0]); az[0]=fmaf(a.x,w_z,az[0]); ah[0]=fmaf(a.x,w_n,ah[0]);
            ar[1]=fmaf(a.y,w_r,ar[1]); az[1]=fmaf(a.y,w_z,az[1]); ah[1]=fmaf(a.y,w_n,ah[1]);
            ar[2]=fmaf(a.z,w_r,ar[2]); az[2]=fmaf(a.z,w_z,az[2]); ah[2]=fmaf(a.z,w_n,ah[2]);
            ar[3]=fmaf(a.w,w_r,ar[3]); az[3]=fmaf(a.w,w_z,az[3]); ah[3]=fmaf(a.w,w_n,ah[3]);
        }
        #pragma unroll 4
        for (int k = 0; k < HID; ++k) {                  // h1-part -> r,z,in
            const float* wr = W2t + (size_t)(HID + k)*G3;
            float w_r = wr[tid], w_z = wr[HID + tid], w_n = wr[2*HID + tid];
            float4 a = *(const float4*)&h1s[k][0];
            ar[0]=fmaf(a.x,w_r,ar[0]); az[0]=fmaf(a.x,w_z,az[0]); ai[0]=fmaf(a.x,w_n,ai[0]);
            ar[1]=fmaf(a.y,w_r,ar[1]); az[1]=fmaf(a.y,w_z,az[1]); ai[1]=fmaf(a.y,w_n,ai[1]);
            ar[2]=fmaf(a.z,w_r,ar[2]); az[2]=fmaf(a.z,w_z,az[2]); ai[2]=fmaf(a.z,w_n,ai[2]);
            ar[3]=fmaf(a.w,w_r,ar[3]); az[3]=fmaf(a.w,w_z,az[3]); ai[3]=fmaf(a.w,w_n,ai[3]);
        }
        float4 q = *(const float4*)&h2s[tid][0];
        float h2old[ROWS] = {q.x, q.y, q.z, q.w};
        float h2n[ROWS];
        #pragma unroll
        for (int b = 0; b < ROWS; ++b) {
            float r  = sigmf(ar[b] + br2);
            float zg = sigmf(az[b] + bz2);
            float n  = tanhf(fmaf(r, ah[b] + bn2, ai[b] + bi2));
            h2n[b] = (1.0f - zg)*n + zg*h2old[b];
        }
        __syncthreads();                                   // D
        *(float4*)&h2s[tid][0] = make_float4(h2n[0], h2n[1], h2n[2], h2n[3]);
        __syncthreads();                                   // E

        // ---- note = tanh(h2) @ W_out^T + b_out; Bernoulli sample (waves 0-3) ----
        if (wv < ROWS) {
            float na[CH];
            #pragma unroll
            for (int c = 0; c < CH; ++c) na[c] = 0.0f;
            for (int kk = ln; kk < HID; kk += 64) {
                float th = tanhf(h2s[kk][wv]);
                #pragma unroll
                for (int c = 0; c < CH; ++c) na[c] = fmaf(th, wouts[kk][c], na[c]);
            }
            #pragma unroll
            for (int c = 0; c < CH; ++c) {
                #pragma unroll
                for (int off = 32; off; off >>= 1)
                    na[c] += __shfl_xor(na[c], off, 64);
            }
            if (ln < CH) {
                int c = ln;
                float note = na[c] + b_out[c];
                float sg = sigmf(note);
                float rv = rnd[((size_t)t*B_TOT + row0 + wv)*CH + c];
                xf[c][wv] = (sg - rv > 0.0f) ? 1.0f : 0.0f;   // feedback bit
                out[((size_t)(row0 + wv)*T_LEN + t)*CH + c] = note;
            }
        }
        __syncthreads();                                   // F
    }
}

extern "C" void kernel_launch(void* const* d_in, const int* in_sizes, int n_in,
                              void* d_out, int out_size, void* d_ws, size_t ws_size,
                              hipStream_t stream)
{
    const float* z     = (const float*)d_in[0];
    const float* se    = (const float*)d_in[1];
    const float* skel  = (const float*)d_in[2];
    const float* cond  = (const float*)d_in[3];
    const float* rnd   = (const float*)d_in[4];
    const float* W_h   = (const float*)d_in[5];
    const float* b_h   = (const float*)d_in[6];
    const float* w_ih1 = (const float*)d_in[7];
    const float* w_hh1 = (const float*)d_in[8];
    const float* b_ih1 = (const float*)d_in[9];
    const float* b_hh1 = (const float*)d_in[10];
    const float* w_ih2 = (const float*)d_in[11];
    const float* w_hh2 = (const float*)d_in[12];
    const float* b_ih2 = (const float*)d_in[13];
    const float* b_hh2 = (const float*)d_in[14];
    const float* W_out = (const float*)d_in[15];
    const float* b_out = (const float*)d_in[16];
    float* ws  = (float*)d_ws;
    float* out = (float*)d_out;

    const int total = SZ_W1T + SZ_W2T + SZ_WHT;
    prep_kernel<<<(total + 255)/256, 256, 0, stream>>>(w_ih1, w_hh1, w_ih2, w_hh2, W_h, ws);
    note_decoder_kernel<<<NWG, NTHR, 0, stream>>>(z, se, skel, cond, rnd, b_h,
                                                  b_ih1, b_hh1, b_ih2, b_hh2,
                                                  W_out, b_out, ws, out);
}

// Round 6
// 314116.528 us; speedup vs baseline: 1.7435x; 1.7435x over previous
//
#include <hip/hip_runtime.h>
#include <math.h>

#define B_TOT 2048
#define T_LEN 1024
#define HID   512
#define CH    9
#define CONDK 272        // 128 + 128 + 16
#define K1X   (2*CH)     // x part of GRU1 K
#define G3    1536       // 3*HID
#define ROWS  8          // batch rows per workgroup
#define NWG   (B_TOT/ROWS)   // 256 = 1 WG per CU
#define NTHR  512
#define PF    8          // prefetch block (k rows per buffer)

// ws layout (floats), k-major separate-plane weight panels (R2 layout)
#define SZ_W1T  ((HID + K1X) * G3)   // 530*1536
#define SZ_W2T  ((2*HID) * G3)       // 1024*1536
#define SZ_WHT  (CONDK * HID)
#define OFF_W1T 0
#define OFF_W2T (OFF_W1T + SZ_W1T)
#define OFF_WHT (OFF_W2T + SZ_W2T)

__global__ void prep_kernel(const float* __restrict__ w_ih1, const float* __restrict__ w_hh1,
                            const float* __restrict__ w_ih2, const float* __restrict__ w_hh2,
                            const float* __restrict__ W_h, float* __restrict__ ws)
{
    int i = blockIdx.x * blockDim.x + threadIdx.x;
    const int total = SZ_W1T + SZ_W2T + SZ_WHT;
    if (i >= total) return;
    if (i < SZ_W1T) {
        int k = i / G3, g = i % G3;
        ws[OFF_W1T + i] = (k < HID) ? w_hh1[g*HID + k] : w_ih1[g*K1X + (k - HID)];
    } else if (i < SZ_W1T + SZ_W2T) {
        int j = i - SZ_W1T;
        int k = j / G3, g = j % G3;
        ws[OFF_W2T + j] = (k < HID) ? w_hh2[g*HID + k] : w_ih2[g*HID + (k - HID)];
    } else {
        int j = i - SZ_W1T - SZ_W2T;
        int k = j / HID, u = j % HID;
        ws[OFF_WHT + j] = W_h[u*CONDK + k];
    }
}

__device__ __forceinline__ float sigmf(float x) { return 1.0f / (1.0f + expf(-x)); }

// load PF weight rows (3 planes) into register buffers
#define LBLK(WP, kbase, WR, WZ, WN)                                        \
    _Pragma("unroll")                                                      \
    for (int j = 0; j < PF; ++j) {                                         \
        const float* wp = (WP) + (size_t)((kbase) + j)*G3;                 \
        WR[j] = wp[tid]; WZ[j] = wp[HID + tid]; WN[j] = wp[2*HID + tid];   \
    }

// 24 FMA per k over PF rows; A2 = third-gate accumulator (ah or ai)
#define GBLK(HS, A2, kbase, WR, WZ, WN)                                    \
    _Pragma("unroll")                                                      \
    for (int j = 0; j < PF; ++j) {                                         \
        int k = (kbase) + j;                                               \
        float4 a0 = *(const float4*)&HS[k][0];                             \
        float4 a1 = *(const float4*)&HS[k][4];                             \
        ar[0]=fmaf(a0.x,WR[j],ar[0]); az[0]=fmaf(a0.x,WZ[j],az[0]); A2[0]=fmaf(a0.x,WN[j],A2[0]); \
        ar[1]=fmaf(a0.y,WR[j],ar[1]); az[1]=fmaf(a0.y,WZ[j],az[1]); A2[1]=fmaf(a0.y,WN[j],A2[1]); \
        ar[2]=fmaf(a0.z,WR[j],ar[2]); az[2]=fmaf(a0.z,WZ[j],az[2]); A2[2]=fmaf(a0.z,WN[j],A2[2]); \
        ar[3]=fmaf(a0.w,WR[j],ar[3]); az[3]=fmaf(a0.w,WZ[j],az[3]); A2[3]=fmaf(a0.w,WN[j],A2[3]); \
        ar[4]=fmaf(a1.x,WR[j],ar[4]); az[4]=fmaf(a1.x,WZ[j],az[4]); A2[4]=fmaf(a1.x,WN[j],A2[4]); \
        ar[5]=fmaf(a1.y,WR[j],ar[5]); az[5]=fmaf(a1.y,WZ[j],az[5]); A2[5]=fmaf(a1.y,WN[j],A2[5]); \
        ar[6]=fmaf(a1.z,WR[j],ar[6]); az[6]=fmaf(a1.z,WZ[j],az[6]); A2[6]=fmaf(a1.z,WN[j],A2[6]); \
        ar[7]=fmaf(a1.w,WR[j],ar[7]); az[7]=fmaf(a1.w,WZ[j],az[7]); A2[7]=fmaf(a1.w,WN[j],A2[7]); \
    }

__global__ __launch_bounds__(NTHR, 2)
void note_decoder_kernel(const float* __restrict__ z, const float* __restrict__ se,
                         const float* __restrict__ skel, const float* __restrict__ cond,
                         const float* __restrict__ rnd,
                         const float* __restrict__ b_h,
                         const float* __restrict__ b_ih1, const float* __restrict__ b_hh1,
                         const float* __restrict__ b_ih2, const float* __restrict__ b_hh2,
                         const float* __restrict__ W_out, const float* __restrict__ b_out,
                         const float* __restrict__ ws,
                         float* __restrict__ out)
{
    // k-major state: h[k][b]; wave-uniform k reads are LDS broadcasts
    __shared__ float h1s[HID][ROWS];
    __shared__ float h2s[HID][ROWS];
    __shared__ float xf[2*CH][ROWS];      // x = [out(9) | skel(9)], k-major
    __shared__ float wouts[HID][CH];

    const float* __restrict__ W1t = ws + OFF_W1T;
    const float* __restrict__ W2t = ws + OFF_W2T;
    const float* __restrict__ Wht = ws + OFF_WHT;

    const int tid  = threadIdx.x;          // owns hidden unit `tid`
    const int row0 = blockIdx.x * ROWS;

    // stage W_out as [u][c]
    for (int i = tid; i < CH*HID; i += NTHR) {
        int c = i / HID, u = i % HID;
        wouts[u][c] = W_out[i];
    }
    // stage zc = [z | skel_encoded | cond] into h2s scratch, k-major
    for (int i = tid; i < ROWS*CONDK; i += NTHR) {
        int b = i / CONDK, k = i % CONDK;
        float v;
        if (k < 128)       v = z[(row0 + b)*128 + k];
        else if (k < 256)  v = se[(row0 + b)*128 + (k - 128)];
        else               v = cond[(row0 + b)*16 + (k - 256)];
        h2s[k][b] = v;
    }
    if (tid < ROWS*CH) xf[tid % CH][tid / CH] = 0.0f;   // out0 = 0 (xf[c][b])
    __syncthreads();

    // h1_0 = tanh(zc @ W_h^T + b_h)  (sequential k per (u,b): R2 order)
    {
        float acc[ROWS];
        #pragma unroll
        for (int b = 0; b < ROWS; ++b) acc[b] = 0.0f;
        for (int k = 0; k < CONDK; ++k) {
            float w = Wht[k*HID + tid];
            float4 a0 = *(const float4*)&h2s[k][0];
            float4 a1 = *(const float4*)&h2s[k][4];
            float hv[ROWS] = {a0.x,a0.y,a0.z,a0.w,a1.x,a1.y,a1.z,a1.w};
            #pragma unroll
            for (int b = 0; b < ROWS; ++b) acc[b] = fmaf(hv[b], w, acc[b]);
        }
        float bh = b_h[tid];
        __syncthreads();   // done reading zc scratch
        #pragma unroll
        for (int b = 0; b < ROWS; ++b) acc[b] = tanhf(acc[b] + bh);
        *(float4*)&h1s[tid][0] = make_float4(acc[0],acc[1],acc[2],acc[3]);
        *(float4*)&h1s[tid][4] = make_float4(acc[4],acc[5],acc[6],acc[7]);
    }
    __syncthreads();

    // hoisted biases
    const float br1 = b_ih1[tid]         + b_hh1[tid];
    const float bz1 = b_ih1[HID + tid]   + b_hh1[HID + tid];
    const float bi1 = b_ih1[2*HID + tid];
    const float bn1 = b_hh1[2*HID + tid];
    const float br2 = b_ih2[tid]         + b_hh2[tid];
    const float bz2 = b_ih2[HID + tid]   + b_hh2[HID + tid];
    const float bi2 = b_ih2[2*HID + tid];
    const float bn2 = b_hh2[2*HID + tid];

    const int wv = tid >> 6, ln = tid & 63;

    float wrA[PF], wzA[PF], wnA[PF];
    float wrB[PF], wzB[PF], wnB[PF];

    for (int t = 0; t < T_LEN; ++t) {
        // stage skel half of x; feedback xf[0..8] from prev step
        if (tid < ROWS*CH) {
            int b = tid / CH, c = tid % CH;
            xf[CH + c][b] = skel[((size_t)(row0 + b)*T_LEN + t)*CH + c];
        }
        __syncthreads();                                   // A

        // ---- GRU1: h-part (512 k, double-buffered prefetch) ----
        float ar[ROWS], az[ROWS], ai[ROWS], ah[ROWS];
        #pragma unroll
        for (int b = 0; b < ROWS; ++b) { ar[b]=0.f; az[b]=0.f; ai[b]=0.f; ah[b]=0.f; }
        LBLK(W1t, 0, wrA, wzA, wnA);
        for (int kb = 0; kb < HID/PF - 2; kb += 2) {
            LBLK(W1t, (kb+1)*PF, wrB, wzB, wnB);
            GBLK(h1s, ah, kb*PF, wrA, wzA, wnA);
            LBLK(W1t, (kb+2)*PF, wrA, wzA, wnA);
            GBLK(h1s, ah, (kb+1)*PF, wrB, wzB, wnB);
        }
        LBLK(W1t, (HID/PF - 1)*PF, wrB, wzB, wnB);
        GBLK(h1s, ah, (HID/PF - 2)*PF, wrA, wzA, wnA);
        GBLK(h1s, ah, (HID/PF - 1)*PF, wrB, wzB, wnB);
        #pragma unroll
        for (int k = 0; k < K1X; ++k) {                  // x-part -> r,z,in
            const float* wr = W1t + (size_t)(HID + k)*G3;
            float w_r = wr[tid], w_z = wr[HID + tid], w_n = wr[2*HID + tid];
            float4 a = *(const float4*)&xf[k][0];
            float4 a1 = *(const float4*)&xf[k][4];
            ar[0]=fmaf(a.x,w_r,ar[0]);  az[0]=fmaf(a.x,w_z,az[0]);  ai[0]=fmaf(a.x,w_n,ai[0]);
            ar[1]=fmaf(a.y,w_r,ar[1]);  az[1]=fmaf(a.y,w_z,az[1]);  ai[1]=fmaf(a.y,w_n,ai[1]);
            ar[2]=fmaf(a.z,w_r,ar[2]);  az[2]=fmaf(a.z,w_z,az[2]);  ai[2]=fmaf(a.z,w_n,ai[2]);
            ar[3]=fmaf(a.w,w_r,ar[3]);  az[3]=fmaf(a.w,w_z,az[3]);  ai[3]=fmaf(a.w,w_n,ai[3]);
            ar[4]=fmaf(a1.x,w_r,ar[4]); az[4]=fmaf(a1.x,w_z,az[4]); ai[4]=fmaf(a1.x,w_n,ai[4]);
            ar[5]=fmaf(a1.y,w_r,ar[5]); az[5]=fmaf(a1.y,w_z,az[5]); ai[5]=fmaf(a1.y,w_n,ai[5]);
            ar[6]=fmaf(a1.z,w_r,ar[6]); az[6]=fmaf(a1.z,w_z,az[6]); ai[6]=fmaf(a1.z,w_n,ai[6]);
            ar[7]=fmaf(a1.w,w_r,ar[7]); az[7]=fmaf(a1.w,w_z,az[7]); ai[7]=fmaf(a1.w,w_n,ai[7]);
        }
        float4 p0 = *(const float4*)&h1s[tid][0];
        float4 p1 = *(const float4*)&h1s[tid][4];
        float h1old[ROWS] = {p0.x,p0.y,p0.z,p0.w,p1.x,p1.y,p1.z,p1.w};
        float h1n[ROWS];
        #pragma unroll
        for (int b = 0; b < ROWS; ++b) {
            float r  = sigmf(ar[b] + br1);
            float zg = sigmf(az[b] + bz1);
            float n  = tanhf(fmaf(r, ah[b] + bn1, ai[b] + bi1));
            h1n[b] = (1.0f - zg)*n + zg*h1old[b];
        }
        __syncthreads();                                   // B: h1 reads done
        *(float4*)&h1s[tid][0] = make_float4(h1n[0],h1n[1],h1n[2],h1n[3]);
        *(float4*)&h1s[tid][4] = make_float4(h1n[4],h1n[5],h1n[6],h1n[7]);
        if (t == 0) {      // hx[1] = hx[0] at i==0
            *(float4*)&h2s[tid][0] = make_float4(h1n[0],h1n[1],h1n[2],h1n[3]);
            *(float4*)&h2s[tid][4] = make_float4(h1n[4],h1n[5],h1n[6],h1n[7]);
        }
        __syncthreads();                                   // C

        // ---- GRU2: h2-part (rows 0..511) then h1-part (rows 512..1023), both prefetched ----
        #pragma unroll
        for (int b = 0; b < ROWS; ++b) { ar[b]=0.f; az[b]=0.f; ai[b]=0.f; ah[b]=0.f; }
        LBLK(W2t, 0, wrA, wzA, wnA);
        for (int kb = 0; kb < HID/PF - 2; kb += 2) {
            LBLK(W2t, (kb+1)*PF, wrB, wzB, wnB);
            GBLK(h2s, ah, kb*PF, wrA, wzA, wnA);
            LBLK(W2t, (kb+2)*PF, wrA, wzA, wnA);
            GBLK(h2s, ah, (kb+1)*PF, wrB, wzB, wnB);
        }
        LBLK(W2t, (HID/PF - 1)*PF, wrB, wzB, wnB);
        GBLK(h2s, ah, (HID/PF - 2)*PF, wrA, wzA, wnA);
        // bridge: prefetch first block of the h1-part while finishing h2-part
        LBLK(W2t, HID, wrA, wzA, wnA);
        GBLK(h2s, ah, (HID/PF - 1)*PF, wrB, wzB, wnB);
        // h1-part: rows HID..2*HID-1 of W2t, reads h1s, third gate -> ai
        for (int kb = 0; kb < HID/PF - 2; kb += 2) {
            LBLK(W2t, HID + (kb+1)*PF, wrB, wzB, wnB);
            GBLK(h1s, ai, kb*PF, wrA, wzA, wnA);
            LBLK(W2t, HID + (kb+2)*PF, wrA, wzA, wnA);
            GBLK(h1s, ai, (kb+1)*PF, wrB, wzB, wnB);
        }
        LBLK(W2t, HID + (HID/PF - 1)*PF, wrB, wzB, wnB);
        GBLK(h1s, ai, (HID/PF - 2)*PF, wrA, wzA, wnA);
        GBLK(h1s, ai, (HID/PF - 1)*PF, wrB, wzB, wnB);
        float4 q0 = *(const float4*)&h2s[tid][0];
        float4 q1 = *(const float4*)&h2s[tid][4];
        float h2old[ROWS] = {q0.x,q0.y,q0.z,q0.w,q1.x,q1.y,q1.z,q1.w};
        float h2n[ROWS];
        #pragma unroll
        for (int b = 0; b < ROWS; ++b) {
            float r  = sigmf(ar[b] + br2);
            float zg = sigmf(az[b] + bz2);
            float n  = tanhf(fmaf(r, ah[b] + bn2, ai[b] + bi2));
            h2n[b] = (1.0f - zg)*n + zg*h2old[b];
        }
        __syncthreads();                                   // D
        *(float4*)&h2s[tid][0] = make_float4(h2n[0],h2n[1],h2n[2],h2n[3]);
        *(float4*)&h2s[tid][4] = make_float4(h2n[4],h2n[5],h2n[6],h2n[7]);
        __syncthreads();                                   // E

        // ---- note = tanh(h2) @ W_out^T + b_out; Bernoulli sample (R2-exact) ----
        {
            float na[CH];
            #pragma unroll
            for (int c = 0; c < CH; ++c) na[c] = 0.0f;
            for (int kk = ln; kk < HID; kk += 64) {
                float th = tanhf(h2s[kk][wv]);
                #pragma unroll
                for (int c = 0; c < CH; ++c) na[c] = fmaf(th, wouts[kk][c], na[c]);
            }
            #pragma unroll
            for (int c = 0; c < CH; ++c) {
                #pragma unroll
                for (int off = 32; off; off >>= 1)
                    na[c] += __shfl_xor(na[c], off, 64);
            }
            if (ln < CH) {
                int c = ln;
                float note = na[c] + b_out[c];
                float sg = sigmf(note);
                float rv = rnd[((size_t)t*B_TOT + row0 + wv)*CH + c];
                xf[c][wv] = (sg - rv > 0.0f) ? 1.0f : 0.0f;   // feedback bit
                out[((size_t)(row0 + wv)*T_LEN + t)*CH + c] = note;
            }
        }
        __syncthreads();                                   // F
    }
}

extern "C" void kernel_launch(void* const* d_in, const int* in_sizes, int n_in,
                              void* d_out, int out_size, void* d_ws, size_t ws_size,
                              hipStream_t stream)
{
    const float* z     = (const float*)d_in[0];
    const float* se    = (const float*)d_in[1];
    const float* skel  = (const float*)d_in[2];
    const float* cond  = (const float*)d_in[3];
    const float* rnd   = (const float*)d_in[4];
    const float* W_h   = (const float*)d_in[5];
    const float* b_h   = (const float*)d_in[6];
    const float* w_ih1 = (const float*)d_in[7];
    const float* w_hh1 = (const float*)d_in[8];
    const float* b_ih1 = (const float*)d_in[9];
    const float* b_hh1 = (const float*)d_in[10];
    const float* w_ih2 = (const float*)d_in[11];
    const float* w_hh2 = (const float*)d_in[12];
    const float* b_ih2 = (const float*)d_in[13];
    const float* b_hh2 = (const float*)d_in[14];
    const float* W_out = (const float*)d_in[15];
    const float* b_out = (const float*)d_in[16];
    float* ws  = (float*)d_ws;
    float* out = (float*)d_out;

    const int total = SZ_W1T + SZ_W2T + SZ_WHT;
    prep_kernel<<<(total + 255)/256, 256, 0, stream>>>(w_ih1, w_hh1, w_ih2, w_hh2, W_h, ws);
    note_decoder_kernel<<<NWG, NTHR, 0, stream>>>(z, se, skel, cond, rnd, b_h,
                                                  b_ih1, b_hh1, b_ih2, b_hh2,
                                                  W_out, b_out, ws, out);
}

// Round 7
// 285572.217 us; speedup vs baseline: 1.9178x; 1.1000x over previous
//
#include <hip/hip_runtime.h>
#include <math.h>

#define B_TOT 2048
#define T_LEN 1024
#define HID   512
#define CH    9
#define CONDK 272        // 128 + 128 + 16
#define K1X   (2*CH)     // x part of GRU1 K
#define G3    1536       // 3*HID
#define ROWS  8          // batch rows per workgroup
#define NWG   (B_TOT/ROWS)   // 256 = 1 WG per CU
#define NTHR  512
#define PF    8          // k-rows per DMA tile
#define NT1   (HID/PF)   // 64 tiles GRU1 h-part
#define NT2   (2*HID/PF) // 128 tiles GRU2

// ws layout (floats), k-major separate-plane weight panels (R2 layout)
#define SZ_W1T  ((HID + K1X) * G3)   // 530*1536
#define SZ_W2T  ((2*HID) * G3)       // 1024*1536
#define SZ_WHT  (CONDK * HID)
#define OFF_W1T 0
#define OFF_W2T (OFF_W1T + SZ_W1T)
#define OFF_WHT (OFF_W2T + SZ_W2T)

__global__ void prep_kernel(const float* __restrict__ w_ih1, const float* __restrict__ w_hh1,
                            const float* __restrict__ w_ih2, const float* __restrict__ w_hh2,
                            const float* __restrict__ W_h, float* __restrict__ ws)
{
    int i = blockIdx.x * blockDim.x + threadIdx.x;
    const int total = SZ_W1T + SZ_W2T + SZ_WHT;
    if (i >= total) return;
    if (i < SZ_W1T) {
        int k = i / G3, g = i % G3;
        ws[OFF_W1T + i] = (k < HID) ? w_hh1[g*HID + k] : w_ih1[g*K1X + (k - HID)];
    } else if (i < SZ_W1T + SZ_W2T) {
        int j = i - SZ_W1T;
        int k = j / G3, g = j % G3;
        ws[OFF_W2T + j] = (k < HID) ? w_hh2[g*HID + k] : w_ih2[g*HID + (k - HID)];
    } else {
        int j = i - SZ_W1T - SZ_W2T;
        int k = j / HID, u = j % HID;
        ws[OFF_WHT + j] = W_h[u*CONDK + k];
    }
}

__device__ __forceinline__ float sigmf(float x) { return 1.0f / (1.0f + expf(-x)); }

typedef __attribute__((address_space(1))) const unsigned int g_u32;
typedef __attribute__((address_space(3))) unsigned int l_u32;
__device__ __forceinline__ void gload_lds16(const void* g, void* l) {
    __builtin_amdgcn_global_load_lds((g_u32*)g, (l_u32*)l, 16, 0, 0);
}

#define WAIT6 asm volatile("s_waitcnt vmcnt(6)" ::: "memory")
#define WAIT0 asm volatile("s_waitcnt vmcnt(0)" ::: "memory")

// issue one PF-row tile (this wave's 64-col slice of 3 planes) into Wb[BUF][w]
#define ISSUE(PANEL, K0, BUF)                                                     \
    {                                                                             \
        const float* pb_ = (PANEL) + (size_t)(K0)*G3;                             \
        _Pragma("unroll")                                                         \
        for (int r_ = 0; r_ < 6; ++r_)                                            \
            gload_lds16(pb_ + choff[r_], &Wb[BUF][w][r_*256]);                    \
    }

// compute one tile: 8 k-rows x (r,z,A2 gates) x 8 batch rows, R2 fmaf order
#define CTILE(HS, A2, K0, BUF)                                                    \
    {                                                                             \
        const float* Wsl_ = &Wb[BUF][w][0];                                       \
        _Pragma("unroll")                                                         \
        for (int j_ = 0; j_ < PF; ++j_) {                                         \
            float w_r = Wsl_[(j_*3+0)*64 + ln];                                   \
            float w_z = Wsl_[(j_*3+1)*64 + ln];                                   \
            float w_n = Wsl_[(j_*3+2)*64 + ln];                                   \
            int k_ = (K0) + j_;                                                   \
            float4 a0 = *(const float4*)&HS[k_][0];                               \
            float4 a1 = *(const float4*)&HS[k_][4];                               \
            ar[0]=fmaf(a0.x,w_r,ar[0]); az[0]=fmaf(a0.x,w_z,az[0]); A2[0]=fmaf(a0.x,w_n,A2[0]); \
            ar[1]=fmaf(a0.y,w_r,ar[1]); az[1]=fmaf(a0.y,w_z,az[1]); A2[1]=fmaf(a0.y,w_n,A2[1]); \
            ar[2]=fmaf(a0.z,w_r,ar[2]); az[2]=fmaf(a0.z,w_z,az[2]); A2[2]=fmaf(a0.z,w_n,A2[2]); \
            ar[3]=fmaf(a0.w,w_r,ar[3]); az[3]=fmaf(a0.w,w_z,az[3]); A2[3]=fmaf(a0.w,w_n,A2[3]); \
            ar[4]=fmaf(a1.x,w_r,ar[4]); az[4]=fmaf(a1.x,w_z,az[4]); A2[4]=fmaf(a1.x,w_n,A2[4]); \
            ar[5]=fmaf(a1.y,w_r,ar[5]); az[5]=fmaf(a1.y,w_z,az[5]); A2[5]=fmaf(a1.y,w_n,A2[5]); \
            ar[6]=fmaf(a1.z,w_r,ar[6]); az[6]=fmaf(a1.z,w_z,az[6]); A2[6]=fmaf(a1.z,w_n,A2[6]); \
            ar[7]=fmaf(a1.w,w_r,ar[7]); az[7]=fmaf(a1.w,w_z,az[7]); A2[7]=fmaf(a1.w,w_n,A2[7]); \
        }                                                                         \
    }

__global__ __launch_bounds__(NTHR, 2)
void note_decoder_kernel(const float* __restrict__ z, const float* __restrict__ se,
                         const float* __restrict__ skel, const float* __restrict__ cond,
                         const float* __restrict__ rnd,
                         const float* __restrict__ b_h,
                         const float* __restrict__ b_ih1, const float* __restrict__ b_hh1,
                         const float* __restrict__ b_ih2, const float* __restrict__ b_hh2,
                         const float* __restrict__ W_out, const float* __restrict__ b_out,
                         const float* __restrict__ ws,
                         float* __restrict__ out)
{
    // weight DMA buffers: [buf][wave][(row*3+seg)*64 + lane]  (6144 B per wave per buf)
    __shared__ float Wb[2][8][PF*3*64];
    __shared__ float h1s[HID][ROWS];
    __shared__ float h2s[HID][ROWS];
    __shared__ float xf[2*CH][ROWS];      // x = [out(9) | skel(9)], k-major
    __shared__ float wouts[HID][CH];

    const float* __restrict__ W1t = ws + OFF_W1T;
    const float* __restrict__ W2t = ws + OFF_W2T;
    const float* __restrict__ Wht = ws + OFF_WHT;

    const int tid  = threadIdx.x;          // owns hidden unit `tid`
    const int w    = tid >> 6;             // wave id
    const int ln   = tid & 63;             // lane
    const int row0 = blockIdx.x * ROWS;

    // per-thread DMA chunk offsets (floats): round r -> chunk c = 4r + ln>>4
    int choff[6];
    #pragma unroll
    for (int r = 0; r < 6; ++r) {
        int c = 4*r + (ln >> 4);
        int j = c / 3, s = c - 3*j;
        choff[r] = j*G3 + s*HID + w*64 + (ln & 15)*4;
    }

    // stage W_out as [u][c]
    for (int i = tid; i < CH*HID; i += NTHR) {
        int c = i / HID, u = i % HID;
        wouts[u][c] = W_out[i];
    }
    // stage zc = [z | skel_encoded | cond] into h2s scratch, k-major
    for (int i = tid; i < ROWS*CONDK; i += NTHR) {
        int b = i / CONDK, k = i % CONDK;
        float v;
        if (k < 128)       v = z[(row0 + b)*128 + k];
        else if (k < 256)  v = se[(row0 + b)*128 + (k - 128)];
        else               v = cond[(row0 + b)*16 + (k - 256)];
        h2s[k][b] = v;
    }
    if (tid < ROWS*CH) xf[tid % CH][tid / CH] = 0.0f;   // out0 = 0 (xf[c][b])
    __syncthreads();

    // h1_0 = tanh(zc @ W_h^T + b_h)  (sequential k per (u,b): R2 order)
    {
        float acc[ROWS];
        #pragma unroll
        for (int b = 0; b < ROWS; ++b) acc[b] = 0.0f;
        for (int k = 0; k < CONDK; ++k) {
            float wv_ = Wht[k*HID + tid];
            float4 a0 = *(const float4*)&h2s[k][0];
            float4 a1 = *(const float4*)&h2s[k][4];
            float hv[ROWS] = {a0.x,a0.y,a0.z,a0.w,a1.x,a1.y,a1.z,a1.w};
            #pragma unroll
            for (int b = 0; b < ROWS; ++b) acc[b] = fmaf(hv[b], wv_, acc[b]);
        }
        float bh = b_h[tid];
        __syncthreads();   // done reading zc scratch
        #pragma unroll
        for (int b = 0; b < ROWS; ++b) acc[b] = tanhf(acc[b] + bh);
        *(float4*)&h1s[tid][0] = make_float4(acc[0],acc[1],acc[2],acc[3]);
        *(float4*)&h1s[tid][4] = make_float4(acc[4],acc[5],acc[6],acc[7]);
    }
    __syncthreads();

    // hoisted biases
    const float br1 = b_ih1[tid]         + b_hh1[tid];
    const float bz1 = b_ih1[HID + tid]   + b_hh1[HID + tid];
    const float bi1 = b_ih1[2*HID + tid];
    const float bn1 = b_hh1[2*HID + tid];
    const float br2 = b_ih2[tid]         + b_hh2[tid];
    const float bz2 = b_ih2[HID + tid]   + b_hh2[HID + tid];
    const float bi2 = b_ih2[2*HID + tid];
    const float bn2 = b_hh2[2*HID + tid];

    for (int t = 0; t < T_LEN; ++t) {
        // stage skel half of x; feedback xf[0..8] from prev step
        if (tid < ROWS*CH) {
            int b = tid / CH, c = tid % CH;
            xf[CH + c][b] = skel[((size_t)(row0 + b)*T_LEN + t)*CH + c];
        }
        __syncthreads();                                   // A

        // ---- GRU1 h-part: 64 tiles, LDS double-buffered DMA ----
        float ar[ROWS], az[ROWS], ai[ROWS], ah[ROWS];
        #pragma unroll
        for (int b = 0; b < ROWS; ++b) { ar[b]=0.f; az[b]=0.f; ai[b]=0.f; ah[b]=0.f; }
        ISSUE(W1t, 0, 0);
        ISSUE(W1t, PF, 1);
        for (int i = 0; i < NT1 - 2; ++i) {
            WAIT6;
            CTILE(h1s, ah, i*PF, (i & 1));
            ISSUE(W1t, (i+2)*PF, (i & 1));
        }
        WAIT6; CTILE(h1s, ah, (NT1-2)*PF, 0);
        WAIT0; CTILE(h1s, ah, (NT1-1)*PF, 1);
        // x-part: 18 rows, scalar streaming (R2-exact)
        #pragma unroll
        for (int k = 0; k < K1X; ++k) {
            const float* wr = W1t + (size_t)(HID + k)*G3;
            float w_r = wr[tid], w_z = wr[HID + tid], w_n = wr[2*HID + tid];
            float4 a  = *(const float4*)&xf[k][0];
            float4 a1 = *(const float4*)&xf[k][4];
            ar[0]=fmaf(a.x,w_r,ar[0]);  az[0]=fmaf(a.x,w_z,az[0]);  ai[0]=fmaf(a.x,w_n,ai[0]);
            ar[1]=fmaf(a.y,w_r,ar[1]);  az[1]=fmaf(a.y,w_z,az[1]);  ai[1]=fmaf(a.y,w_n,ai[1]);
            ar[2]=fmaf(a.z,w_r,ar[2]);  az[2]=fmaf(a.z,w_z,az[2]);  ai[2]=fmaf(a.z,w_n,ai[2]);
            ar[3]=fmaf(a.w,w_r,ar[3]);  az[3]=fmaf(a.w,w_z,az[3]);  ai[3]=fmaf(a.w,w_n,ai[3]);
            ar[4]=fmaf(a1.x,w_r,ar[4]); az[4]=fmaf(a1.x,w_z,az[4]); ai[4]=fmaf(a1.x,w_n,ai[4]);
            ar[5]=fmaf(a1.y,w_r,ar[5]); az[5]=fmaf(a1.y,w_z,az[5]); ai[5]=fmaf(a1.y,w_n,ai[5]);
            ar[6]=fmaf(a1.z,w_r,ar[6]); az[6]=fmaf(a1.z,w_z,az[6]); ai[6]=fmaf(a1.z,w_n,ai[6]);
            ar[7]=fmaf(a1.w,w_r,ar[7]); az[7]=fmaf(a1.w,w_z,az[7]); ai[7]=fmaf(a1.w,w_n,ai[7]);
        }
        float4 p0 = *(const float4*)&h1s[tid][0];
        float4 p1 = *(const float4*)&h1s[tid][4];
        float h1old[ROWS] = {p0.x,p0.y,p0.z,p0.w,p1.x,p1.y,p1.z,p1.w};
        float h1n[ROWS];
        #pragma unroll
        for (int b = 0; b < ROWS; ++b) {
            float r  = sigmf(ar[b] + br1);
            float zg = sigmf(az[b] + bz1);
            float n  = tanhf(fmaf(r, ah[b] + bn1, ai[b] + bi1));
            h1n[b] = (1.0f - zg)*n + zg*h1old[b];
        }
        __syncthreads();                                   // B: h1 reads done
        *(float4*)&h1s[tid][0] = make_float4(h1n[0],h1n[1],h1n[2],h1n[3]);
        *(float4*)&h1s[tid][4] = make_float4(h1n[4],h1n[5],h1n[6],h1n[7]);
        if (t == 0) {      // hx[1] = hx[0] at i==0
            *(float4*)&h2s[tid][0] = make_float4(h1n[0],h1n[1],h1n[2],h1n[3]);
            *(float4*)&h2s[tid][4] = make_float4(h1n[4],h1n[5],h1n[6],h1n[7]);
        }
        __syncthreads();                                   // C

        // ---- GRU2: 128 tiles (h2-part rows 0..511 -> ah, h1-part rows 512..1023 -> ai) ----
        #pragma unroll
        for (int b = 0; b < ROWS; ++b) { ar[b]=0.f; az[b]=0.f; ai[b]=0.f; ah[b]=0.f; }
        ISSUE(W2t, 0, 0);
        ISSUE(W2t, PF, 1);
        for (int i = 0; i < NT2/2; ++i) {                  // tiles 0..63: h2-part
            WAIT6;
            CTILE(h2s, ah, i*PF, (i & 1));
            ISSUE(W2t, (i+2)*PF, (i & 1));
        }
        for (int i = NT2/2; i < NT2 - 2; ++i) {            // tiles 64..125: h1-part
            WAIT6;
            CTILE(h1s, ai, (i - NT2/2)*PF, (i & 1));
            ISSUE(W2t, (i+2)*PF, (i & 1));
        }
        WAIT6; CTILE(h1s, ai, (NT2/2 - 2)*PF, 0);
        WAIT0; CTILE(h1s, ai, (NT2/2 - 1)*PF, 1);
        float4 q0 = *(const float4*)&h2s[tid][0];
        float4 q1 = *(const float4*)&h2s[tid][4];
        float h2old[ROWS] = {q0.x,q0.y,q0.z,q0.w,q1.x,q1.y,q1.z,q1.w};
        float h2n[ROWS];
        #pragma unroll
        for (int b = 0; b < ROWS; ++b) {
            float r  = sigmf(ar[b] + br2);
            float zg = sigmf(az[b] + bz2);
            float n  = tanhf(fmaf(r, ah[b] + bn2, ai[b] + bi2));
            h2n[b] = (1.0f - zg)*n + zg*h2old[b];
        }
        __syncthreads();                                   // D
        *(float4*)&h2s[tid][0] = make_float4(h2n[0],h2n[1],h2n[2],h2n[3]);
        *(float4*)&h2s[tid][4] = make_float4(h2n[4],h2n[5],h2n[6],h2n[7]);
        __syncthreads();                                   // E

        // ---- note = tanh(h2) @ W_out^T + b_out; Bernoulli sample (R2-exact) ----
        {
            float na[CH];
            #pragma unroll
            for (int c = 0; c < CH; ++c) na[c] = 0.0f;
            for (int kk = ln; kk < HID; kk += 64) {
                float th = tanhf(h2s[kk][w]);
                #pragma unroll
                for (int c = 0; c < CH; ++c) na[c] = fmaf(th, wouts[kk][c], na[c]);
            }
            #pragma unroll
            for (int c = 0; c < CH; ++c) {
                #pragma unroll
                for (int off = 32; off; off >>= 1)
                    na[c] += __shfl_xor(na[c], off, 64);
            }
            if (ln < CH) {
                int c = ln;
                float note = na[c] + b_out[c];
                float sg = sigmf(note);
                float rv = rnd[((size_t)t*B_TOT + row0 + w)*CH + c];
                xf[c][w] = (sg - rv > 0.0f) ? 1.0f : 0.0f;   // feedback bit
                out[((size_t)(row0 + w)*T_LEN + t)*CH + c] = note;
            }
        }
        __syncthreads();                                   // F
    }
}

extern "C" void kernel_launch(void* const* d_in, const int* in_sizes, int n_in,
                              void* d_out, int out_size, void* d_ws, size_t ws_size,
                              hipStream_t stream)
{
    const float* z     = (const float*)d_in[0];
    const float* se    = (const float*)d_in[1];
    const float* skel  = (const float*)d_in[2];
    const float* cond  = (const float*)d_in[3];
    const float* rnd   = (const float*)d_in[4];
    const float* W_h   = (const float*)d_in[5];
    const float* b_h   = (const float*)d_in[6];
    const float* w_ih1 = (const float*)d_in[7];
    const float* w_hh1 = (const float*)d_in[8];
    const float* b_ih1 = (const float*)d_in[9];
    const float* b_hh1 = (const float*)d_in[10];
    const float* w_ih2 = (const float*)d_in[11];
    const float* w_hh2 = (const float*)d_in[12];
    const float* b_ih2 = (const float*)d_in[13];
    const float* b_hh2 = (const float*)d_in[14];
    const float* W_out = (const float*)d_in[15];
    const float* b_out = (const float*)d_in[16];
    float* ws  = (float*)d_ws;
    float* out = (float*)d_out;

    const int total = SZ_W1T + SZ_W2T + SZ_WHT;
    prep_kernel<<<(total + 255)/256, 256, 0, stream>>>(w_ih1, w_hh1, w_ih2, w_hh2, W_h, ws);
    note_decoder_kernel<<<NWG, NTHR, 0, stream>>>(z, se, skel, cond, rnd, b_h,
                                                  b_ih1, b_hh1, b_ih2, b_hh2,
                                                  W_out, b_out, ws, out);
}